// Round 3
// baseline (280.609 us; speedup 1.0000x reference)
//
#include <hip/hip_runtime.h>

// BMAttention: 4 cross-attention combos, B=4 L=S=2048 H=8 E=D=64, fp32 in/out.
// R8: occupancy push. R7 showed MFMA ~71us, VALU/trans ~70us, LDS ~82us all
// ~50% busy and summing (no overlap) at 3.66 blocks/CU (32KB LDS limit).
// Halve the staging tile to 32 keys -> 16KB LDS double-buffer; the 64-key
// tile was already two contiguous 4KB sub-blocks in wsK/wsV, so the loop
// becomes 64 subtile iterations, 2 global_load_lds/thread/stage. Register
// limit (~95 incl. acc) now binds at ~5 blocks/CU (__launch_bounds__(256,5)).
// All MFMAs 16x16x32 (K=32) via key-permuted V frags:
//   key(q,j) = m*32 + (j>=4)*16 + q*4 + (j&3)

typedef _Float16 half8 __attribute__((ext_vector_type(8)));
typedef _Float16 half4 __attribute__((ext_vector_type(4)));
typedef _Float16 half2t __attribute__((ext_vector_type(2)));
typedef float f32x4 __attribute__((ext_vector_type(4)));

#define MFMA_QK(a, b, c) __builtin_amdgcn_mfma_f32_16x16x32_f16(a, b, c, 0, 0, 0)
#define MFMA_PV(a, b, c) __builtin_amdgcn_mfma_f32_16x16x16f16(a, b, c, 0, 0, 0)

static __device__ inline half2t pk(float a, float b) {
    return __builtin_bit_cast(half2t, __builtin_amdgcn_cvt_pkrtz(a, b));
}

static __device__ __forceinline__ void gload_lds16(const _Float16* g, _Float16* l) {
    __builtin_amdgcn_global_load_lds(
        (const __attribute__((address_space(1))) unsigned int*)g,
        (__attribute__((address_space(3))) unsigned int*)l, 16, 0, 0);
}

// scale * log2(e): logits computed directly in base-2 (folded into K prepass)
#define QSCALE 0.1803368867f

#define TENS_ELEMS 4194304   // B*S*H*E = 4*2048*8*64

// ---------------------------------------------------------------------------
// Prepass: grid (32 tiles, 32 bh, 4): z = set + 2*isV.
//  K path: wsK[set][bh][t][(nb*2+kc)*64 + lane]*8 = QSCALE*K[s=t*64+nb*16+l16][e=kc*32+q*8+j]
//  V path (K=32 B-frag order): wsV[set][bh][t][((m*4+db)*64 + lane)*8], elem j =
//          V[s=t*64 + m*32 + (j>=4)*16 + q*4 + (j&3)][d=db*16+l16]
// where lane = q*16+l16.  Tile block = 4096 halves = 8 KB.
// ---------------------------------------------------------------------------
__global__ __launch_bounds__(256) void prep_kernel(
    const float* __restrict__ kw, const float* __restrict__ km,
    const float* __restrict__ vw, const float* __restrict__ vm,
    _Float16* __restrict__ wsK, _Float16* __restrict__ wsV)
{
    const int t = blockIdx.x, bh = blockIdx.y, z = blockIdx.z;
    const int set = z & 1;
    const int b = bh >> 3, h = bh & 7;
    const int tid = threadIdx.x;
    const size_t headOff = ((size_t)b * 2048) * 512 + (size_t)h * 64;
    const size_t tileOff = ((((size_t)set * 32 + bh) * 32) + t) * 4096;

    __shared__ _Float16 T[64 * 68];

    if (z < 2) {
        // ---- K: fragment-ordered, scaled by QSCALE ----
        const float* kb = (set ? km : kw) + headOff;
        _Float16* dst = wsK + tileOff;
#pragma unroll
        for (int w = 0; w < 2; ++w) {
            const int c = tid + w * 256;                 // chunk 0..511
            const int l16 = c & 15, q = (c >> 4) & 3, kc = (c >> 6) & 1, nb = (c >> 7) & 3;
            const float* p = kb + (size_t)(t * 64 + nb * 16 + l16) * 512 + kc * 32 + q * 8;
            float4 x = *(const float4*)p;
            float4 y = *(const float4*)(p + 4);
            half2t h0 = pk(x.x * QSCALE, x.y * QSCALE), h1 = pk(x.z * QSCALE, x.w * QSCALE);
            half2t h2 = pk(y.x * QSCALE, y.y * QSCALE), h3 = pk(y.z * QSCALE, y.w * QSCALE);
            half8 o = {h0.x, h0.y, h1.x, h1.y, h2.x, h2.y, h3.x, h3.y};
            *(half8*)(dst + (size_t)c * 8) = o;
        }
    } else {
        // ---- V: transpose via LDS, then key-permuted K=32 B-frag order ----
        const float* vb = (set ? vm : vw) + headOff;
        const int s_row = tid >> 2, cg = (tid & 3) * 16;
        const float* row = vb + (size_t)(t * 64 + s_row) * 512 + cg;
#pragma unroll
        for (int k4 = 0; k4 < 4; ++k4) {
            float4 v = *(const float4*)(row + k4 * 4);
            const int d0 = cg + k4 * 4;
            T[(d0 + 0) * 68 + s_row] = (_Float16)v.x;
            T[(d0 + 1) * 68 + s_row] = (_Float16)v.y;
            T[(d0 + 2) * 68 + s_row] = (_Float16)v.z;
            T[(d0 + 3) * 68 + s_row] = (_Float16)v.w;
        }
        __syncthreads();
        _Float16* dst = wsV + tileOff;
#pragma unroll
        for (int w = 0; w < 2; ++w) {
            const int c = tid + w * 256;                 // half8 slot 0..511
            const int lane = c & 63, db = (c >> 6) & 3, m = (c >> 8) & 1;
            const int l16 = lane & 15, q = lane >> 4;
            const _Float16* tp = &T[(db * 16 + l16) * 68 + m * 32 + q * 4];
            half4 a = *(const half4*)tp;          // keys m*32 + q*4 + 0..3
            half4 b2 = *(const half4*)(tp + 16);  // keys m*32 + 16 + q*4 + 0..3
            half8 o = {a[0], a[1], a[2], a[3], b2[0], b2[1], b2[2], b2[3]};
            *(half8*)(dst + (size_t)c * 8) = o;
        }
    }
}

// ---------------------------------------------------------------------------
// Main kernel: double-buffered 16KB LDS staging of 32-key frag sub-blocks.
// Each wave owns 16 q-rows for 2 sources. All MFMAs K=32.
// ---------------------------------------------------------------------------
__global__ __launch_bounds__(256, 5) void bm_attn_main(
    const float* __restrict__ qw, const float* __restrict__ qm,
    const _Float16* __restrict__ wsK, const _Float16* __restrict__ wsV,
    float* __restrict__ out)
{
    const int ltile = blockIdx.x, bh = blockIdx.y, set = blockIdx.z;
    const int b = bh >> 3, h = bh & 7;
    const float* Q0 = set ? qm : qw;
    const float* Q1 = set ? qw : qm;
    const int c0 = set ? 1 : 0, c1 = set ? 2 : 3;

    const int tid = threadIdx.x;
    const int wave = tid >> 6, lane = tid & 63;
    const int quad = lane >> 4, l16 = lane & 15;

    __shared__ __align__(16) _Float16 ldsK[2][2048];   // 2 x 4 KB
    __shared__ __align__(16) _Float16 ldsV[2][2048];   // 2 x 4 KB

    const size_t headOff = ((size_t)b * 2048) * 512 + (size_t)h * 64;
    const size_t tileBase = (((size_t)set * 32 + bh) * 32) * 4096;
    const _Float16* tK = wsK + tileBase;
    const _Float16* tV = wsV + tileBase;

    // ---- Q B-fragments (n=qrow=l16, k=e=quad*8+j), unscaled (K carries scale)
    const int rowBase = ltile * 64 + wave * 16;
    half8 qB[2][2];
    {
        const float* qs[2] = { Q0 + headOff, Q1 + headOff };
#pragma unroll
        for (int s = 0; s < 2; ++s)
#pragma unroll
            for (int kc = 0; kc < 2; ++kc) {
                const float* p = qs[s] + (size_t)(rowBase + l16) * 512 + kc * 32 + quad * 8;
                float4 x = *(const float4*)p;
                float4 y = *(const float4*)(p + 4);
                half2t h0 = pk(x.x, x.y), h1 = pk(x.z, x.w);
                half2t h2 = pk(y.x, y.y), h3 = pk(y.z, y.w);
                qB[s][kc] = (half8){h0.x, h0.y, h1.x, h1.y, h2.x, h2.y, h3.x, h3.y};
            }
    }

    f32x4 accO[2][4];
    f32x4 rsD[2];
#pragma unroll
    for (int s = 0; s < 2; ++s) {
        rsD[s] = (f32x4){0.f, 0.f, 0.f, 0.f};
#pragma unroll
        for (int d = 0; d < 4; ++d) accO[s][d] = (f32x4){0.f, 0.f, 0.f, 0.f};
    }
    const half8 ones8 = {(_Float16)1.f, (_Float16)1.f, (_Float16)1.f, (_Float16)1.f,
                         (_Float16)1.f, (_Float16)1.f, (_Float16)1.f, (_Float16)1.f};

    // ---- stage 32-key subtile st into LDS buffer buf (pure linear copy)
    auto stage = [&](int st, int buf) {
        const size_t off = (size_t)st * 2048 + tid * 8;
        _Float16* lK = &ldsK[buf][wave * 512];   // wave-uniform base; HW adds lane*16B
        _Float16* lV = &ldsV[buf][wave * 512];
        gload_lds16(tK + off, lK);
        gload_lds16(tV + off, lV);
    };

    stage(0, 0);
    __syncthreads();
    int cur = 0;

#pragma unroll 1
    for (int st = 0; st < 64; ++st) {
        if (st + 1 < 64) stage(st + 1, cur ^ 1);

        const _Float16* kt = &ldsK[cur][lane * 8];
        const _Float16* vt = &ldsV[cur][lane * 8];

        // ---- S^T for 32 keys = two 16-key blocks ----
        half8 k00 = *(const half8*)(kt + 0 * 512);   // nb0, kc0
        half8 k01 = *(const half8*)(kt + 1 * 512);   // nb0, kc1
        half8 k10 = *(const half8*)(kt + 2 * 512);   // nb1, kc0
        half8 k11 = *(const half8*)(kt + 3 * 512);   // nb1, kc1
        f32x4 z = {0.f, 0.f, 0.f, 0.f};
        f32x4 s00 = MFMA_QK(k00, qB[0][0], z);
        s00 = MFMA_QK(k01, qB[0][1], s00);            // src0, keys q*4+r
        f32x4 s01 = MFMA_QK(k10, qB[0][0], z);
        s01 = MFMA_QK(k11, qB[0][1], s01);            // src0, keys 16+q*4+r
        f32x4 s10 = MFMA_QK(k00, qB[1][0], z);
        s10 = MFMA_QK(k01, qB[1][1], s10);
        f32x4 s11 = MFMA_QK(k10, qB[1][0], z);
        s11 = MFMA_QK(k11, qB[1][1], s11);

        // ---- P = exp2(logit), packed straight into K=32 A-frags ----
        half2t a0 = pk(__builtin_amdgcn_exp2f(s00[0]), __builtin_amdgcn_exp2f(s00[1]));
        half2t a1 = pk(__builtin_amdgcn_exp2f(s00[2]), __builtin_amdgcn_exp2f(s00[3]));
        half2t a2 = pk(__builtin_amdgcn_exp2f(s01[0]), __builtin_amdgcn_exp2f(s01[1]));
        half2t a3 = pk(__builtin_amdgcn_exp2f(s01[2]), __builtin_amdgcn_exp2f(s01[3]));
        half8 pa0 = {a0.x, a0.y, a1.x, a1.y, a2.x, a2.y, a3.x, a3.y};
        half2t b0 = pk(__builtin_amdgcn_exp2f(s10[0]), __builtin_amdgcn_exp2f(s10[1]));
        half2t b1 = pk(__builtin_amdgcn_exp2f(s10[2]), __builtin_amdgcn_exp2f(s10[3]));
        half2t b2 = pk(__builtin_amdgcn_exp2f(s11[0]), __builtin_amdgcn_exp2f(s11[1]));
        half2t b3 = pk(__builtin_amdgcn_exp2f(s11[2]), __builtin_amdgcn_exp2f(s11[3]));
        half8 pa1 = {b0.x, b0.y, b1.x, b1.y, b2.x, b2.y, b3.x, b3.y};

        // ---- row-sums via ones-MFMA, K=32 (D reg r = rowsum of qrow=quad*4+r)
        rsD[0] = MFMA_QK(pa0, ones8, rsD[0]);
        rsD[1] = MFMA_QK(pa1, ones8, rsD[1]);

        // ---- O += P(32 keys) * V(32 keys), K=32, key-permuted V B-frags
#pragma unroll
        for (int db = 0; db < 4; ++db) {
            half8 bv = *(const half8*)(vt + db * 512);
            accO[0][db] = MFMA_QK(pa0, bv, accO[0][db]);
            accO[1][db] = MFMA_QK(pa1, bv, accO[1][db]);
        }

        __syncthreads();
        cur ^= 1;
    }

    // ---- epilogue: rsD reg r IS the row-sum for qrow=quad*4+r; no shuffles ----
#pragma unroll
    for (int s = 0; s < 2; ++s) {
        const int c = (s == 0) ? c0 : c1;
        float* ob = out + (size_t)c * TENS_ELEMS + headOff;
#pragma unroll
        for (int r = 0; r < 4; ++r) {
            const float inv = 1.0f / rsD[s][r];
            const int row = rowBase + quad * 4 + r;
#pragma unroll
            for (int db = 0; db < 4; ++db) {
                ob[(size_t)row * 512 + db * 16 + l16] = accO[s][db][r] * inv;
            }
        }
    }
}

// ---------------------------------------------------------------------------
// Fallback (ws too small): R4's self-contained LDS-staging kernel.
// ---------------------------------------------------------------------------
__global__ __launch_bounds__(256) void bm_attn_fallback(
    const float* __restrict__ qw, const float* __restrict__ kw, const float* __restrict__ vw,
    const float* __restrict__ qm, const float* __restrict__ km, const float* __restrict__ vm,
    float* __restrict__ out)
{
    const int ltile = blockIdx.x, bh = blockIdx.y, set = blockIdx.z;
    const int b = bh >> 3, h = bh & 7;
    const float* Q0 = set ? qm : qw;
    const float* Q1 = set ? qw : qm;
    const int c0 = set ? 1 : 0, c1 = set ? 2 : 3;
    const int tid = threadIdx.x;
    const int wave = tid >> 6, lane = tid & 63;
    const int quad = lane >> 4, l16 = lane & 15;
    __shared__ __align__(16) _Float16 Kt[64 * 72];
    __shared__ __align__(16) _Float16 Vt[64 * 72];
    const size_t headOff = ((size_t)b * 2048) * 512 + (size_t)h * 64;
    const float* kb = (set ? km : kw) + headOff;
    const float* vb = (set ? vm : vw) + headOff;
    const int rowBase = ltile * 64 + wave * 16;
    half8 qB[2][2];
    {
        const float* qs[2] = { Q0 + headOff, Q1 + headOff };
#pragma unroll
        for (int s = 0; s < 2; ++s)
#pragma unroll
            for (int kc = 0; kc < 2; ++kc) {
                const float* p = qs[s] + (size_t)(rowBase + l16) * 512 + kc * 32 + quad * 8;
                half8 q;
#pragma unroll
                for (int j = 0; j < 8; ++j) q[j] = (_Float16)(p[j] * QSCALE);
                qB[s][kc] = q;
            }
    }
    f32x4 accO[2][4];
#pragma unroll
    for (int s = 0; s < 2; ++s)
#pragma unroll
        for (int d = 0; d < 4; ++d) accO[s][d] = (f32x4){0.f, 0.f, 0.f, 0.f};
    float rs0 = 0.f, rs1 = 0.f;
#pragma unroll 1
    for (int tile = 0; tile < 32; ++tile) {
        const int s0 = tile * 64;
        __syncthreads();
        {
            const int r0 = tid >> 4, f4 = (tid & 15) * 4;
#pragma unroll
            for (int p4 = 0; p4 < 4; ++p4) {
                const int row = p4 * 16 + r0;
                float4 v = *(const float4*)(kb + (size_t)(s0 + row) * 512 + f4);
                half2t a = pk(v.x, v.y), b2 = pk(v.z, v.w);
                half4 o = {a.x, a.y, b2.x, b2.y};
                *(half4*)&Kt[row * 72 + f4] = o;
            }
            const int sl = tid & 63, dq = tid >> 6;
            const float* vrow = vb + (size_t)(s0 + sl) * 512;
#pragma unroll
            for (int i = 0; i < 4; ++i) {
                const int d0 = dq * 16 + i * 4;
                float4 v = *(const float4*)(vrow + d0);
                Vt[(d0 + 0) * 72 + sl] = (_Float16)v.x;
                Vt[(d0 + 1) * 72 + sl] = (_Float16)v.y;
                Vt[(d0 + 2) * 72 + sl] = (_Float16)v.z;
                Vt[(d0 + 3) * 72 + sl] = (_Float16)v.w;
            }
        }
        __syncthreads();
#pragma unroll
        for (int nb = 0; nb < 4; ++nb) {
            half8 k0 = *(const half8*)&Kt[(nb * 16 + l16) * 72 + quad * 8];
            half8 k1 = *(const half8*)&Kt[(nb * 16 + l16) * 72 + 32 + quad * 8];
            f32x4 z = {0.f, 0.f, 0.f, 0.f};
            f32x4 st0 = MFMA_QK(k0, qB[0][0], z);
            st0 = MFMA_QK(k1, qB[0][1], st0);
            f32x4 st1 = MFMA_QK(k0, qB[1][0], z);
            st1 = MFMA_QK(k1, qB[1][1], st1);
            half2t p00 = pk(__builtin_amdgcn_exp2f(st0[0]), __builtin_amdgcn_exp2f(st0[1]));
            half2t p01 = pk(__builtin_amdgcn_exp2f(st0[2]), __builtin_amdgcn_exp2f(st0[3]));
            half2t p10 = pk(__builtin_amdgcn_exp2f(st1[0]), __builtin_amdgcn_exp2f(st1[1]));
            half2t p11 = pk(__builtin_amdgcn_exp2f(st1[2]), __builtin_amdgcn_exp2f(st1[3]));
            rs0 += (float)p00.x + (float)p00.y + (float)p01.x + (float)p01.y;
            rs1 += (float)p10.x + (float)p10.y + (float)p11.x + (float)p11.y;
            half4 ph0 = {p00.x, p00.y, p01.x, p01.y};
            half4 ph1 = {p10.x, p10.y, p11.x, p11.y};
#pragma unroll
            for (int db = 0; db < 4; ++db) {
                half4 bv = *(const half4*)&Vt[(db * 16 + l16) * 72 + nb * 16 + quad * 4];
                accO[0][db] = MFMA_PV(ph0, bv, accO[0][db]);
                accO[1][db] = MFMA_PV(ph1, bv, accO[1][db]);
            }
        }
    }
#pragma unroll
    for (int s = 0; s < 2; ++s) {
        float rs = (s == 0) ? rs0 : rs1;
        rs += __shfl_xor(rs, 16);
        rs += __shfl_xor(rs, 32);
        const float inv = 1.0f / rs;
        const int c = (s == 0) ? c0 : c1;
        float* ob = out + (size_t)c * TENS_ELEMS + headOff;
#pragma unroll
        for (int r = 0; r < 4; ++r) {
            const float invr = __shfl(inv, quad * 4 + r);
            const int row = rowBase + quad * 4 + r;
#pragma unroll
            for (int db = 0; db < 4; ++db) {
                ob[(size_t)row * 512 + db * 16 + l16] = accO[s][db][r] * invr;
            }
        }
    }
}

extern "C" void kernel_launch(void* const* d_in, const int* in_sizes, int n_in,
                              void* d_out, int out_size, void* d_ws, size_t ws_size,
                              hipStream_t stream) {
    const float* qw = (const float*)d_in[0];
    const float* kw = (const float*)d_in[1];
    const float* vw = (const float*)d_in[2];
    const float* qm = (const float*)d_in[3];
    const float* km = (const float*)d_in[4];
    const float* vm = (const float*)d_in[5];
    float* out = (float*)d_out;

    dim3 block(256);
    const size_t NEED = (size_t)4 * TENS_ELEMS * sizeof(_Float16);  // 32 MiB

    if (ws_size >= NEED) {
        _Float16* wsK = (_Float16*)d_ws;                 // [2][32][32][4096] frag-ordered K (scaled)
        _Float16* wsV = wsK + (size_t)2 * TENS_ELEMS;    // [2][32][32][4096] key-permuted K=32 V frags
        prep_kernel<<<dim3(32, 32, 4), block, 0, stream>>>(kw, km, vw, vm, wsK, wsV);
        bm_attn_main<<<dim3(32, 32, 2), block, 0, stream>>>(qw, qm, wsK, wsV, out);
    } else {
        bm_attn_fallback<<<dim3(32, 32, 2), block, 0, stream>>>(qw, kw, vw, qm, km, vm, out);
    }
}

// Round 4
// 271.998 us; speedup vs baseline: 1.0317x; 1.0317x over previous
//
#include <hip/hip_runtime.h>

// BMAttention: 4 cross-attention combos, B=4 L=S=2048 H=8 E=D=64, fp32 in/out.
// R9: two independent fixes.
//  (a) Main: 32 q-rows per wave (2 row-blocks x 2 sources) -> each K/V frag
//      ds_read_b128 feeds 4 MFMAs (was 2); LDS traffic and barriers per unit
//      work halve. 64-key tiles (R7 cadence; R8's 32-key halving regressed).
//      Grid (16,32,2)=1024 + bijective XCD swizzle for per-XCD L2 ws reuse.
//  (b) Prepass: fully-coalesced float4 tile loads (16 lanes = one 256B row)
//      bounced through padded LDS; identical ws frag format as before.
// All MFMAs 16x16x32 (K=32) via key-permuted V frags:
//   key(q,j) = m*32 + (j>=4)*16 + q*4 + (j&3)

typedef _Float16 half8 __attribute__((ext_vector_type(8)));
typedef _Float16 half4 __attribute__((ext_vector_type(4)));
typedef _Float16 half2t __attribute__((ext_vector_type(2)));
typedef float f32x4 __attribute__((ext_vector_type(4)));

#define MFMA_QK(a, b, c) __builtin_amdgcn_mfma_f32_16x16x32_f16(a, b, c, 0, 0, 0)
#define MFMA_PV(a, b, c) __builtin_amdgcn_mfma_f32_16x16x16f16(a, b, c, 0, 0, 0)

static __device__ inline half2t pk(float a, float b) {
    return __builtin_bit_cast(half2t, __builtin_amdgcn_cvt_pkrtz(a, b));
}

static __device__ __forceinline__ void gload_lds16(const _Float16* g, _Float16* l) {
    __builtin_amdgcn_global_load_lds(
        (const __attribute__((address_space(1))) unsigned int*)g,
        (__attribute__((address_space(3))) unsigned int*)l, 16, 0, 0);
}

// scale * log2(e): logits computed directly in base-2 (folded into K prepass)
#define QSCALE 0.1803368867f

#define TENS_ELEMS 4194304   // B*S*H*E = 4*2048*8*64

// ---------------------------------------------------------------------------
// Prepass: grid (32 tiles, 32 bh, 4): z = set + 2*isV.
//  K path: wsK[set][bh][t][(nb*2+kc)*64 + lane]*8 = QSCALE*K[s=t*64+nb*16+l16][e=kc*32+q*8+j]
//  V path (K=32 B-frag order): wsV[set][bh][t][((m*4+db)*64 + lane)*8], elem j =
//          V[s=t*64 + m*32 + (j>=4)*16 + q*4 + (j&3)][d=db*16+l16]
// where lane = q*16+l16.  Tile block = 4096 halves = 8 KB.
// Loads: 16 lanes x float4 cover one full 256B row -> fully coalesced.
// ---------------------------------------------------------------------------
__global__ __launch_bounds__(256) void prep_kernel(
    const float* __restrict__ kw, const float* __restrict__ km,
    const float* __restrict__ vw, const float* __restrict__ vm,
    _Float16* __restrict__ wsK, _Float16* __restrict__ wsV)
{
    const int t = blockIdx.x, bh = blockIdx.y, z = blockIdx.z;
    const int set = z & 1;
    const int b = bh >> 3, h = bh & 7;
    const int tid = threadIdx.x;
    const size_t headOff = ((size_t)b * 2048) * 512 + (size_t)h * 64;
    const size_t tileOff = ((((size_t)set * 32 + bh) * 32) + t) * 4096;
    const int lr = tid >> 4, lc = (tid & 15) * 4;   // row-of-16, col group

    if (z < 2) {
        // ---- K: coalesced load -> LDS [row][col] (stride 72) -> frag emit ----
        __shared__ _Float16 T[64 * 72];
        const float* kb = (set ? km : kw) + headOff + (size_t)t * 64 * 512;
#pragma unroll
        for (int i = 0; i < 4; ++i) {
            const int row = i * 16 + lr;
            float4 v = *(const float4*)(kb + (size_t)row * 512 + lc);
            half2t h0 = pk(v.x * QSCALE, v.y * QSCALE);
            half2t h1 = pk(v.z * QSCALE, v.w * QSCALE);
            half4 o = {h0.x, h0.y, h1.x, h1.y};
            *(half4*)&T[row * 72 + lc] = o;
        }
        __syncthreads();
        _Float16* dst = wsK + tileOff;
#pragma unroll
        for (int w = 0; w < 2; ++w) {
            const int c = tid + w * 256;                 // chunk 0..511
            const int l16 = c & 15, q = (c >> 4) & 3, kc = (c >> 6) & 1, nb = (c >> 7) & 3;
            half8 o = *(const half8*)&T[(nb * 16 + l16) * 72 + kc * 32 + q * 8];
            *(half8*)(dst + (size_t)c * 8) = o;
        }
    } else {
        // ---- V: coalesced load -> transposed LDS [d][s] (stride 76) -> emit ----
        __shared__ _Float16 Tv[64 * 76];
        const float* vb = (set ? vm : vw) + headOff + (size_t)t * 64 * 512;
#pragma unroll
        for (int i = 0; i < 4; ++i) {
            const int row = i * 16 + lr;                 // s_local
            float4 v = *(const float4*)(vb + (size_t)row * 512 + lc);
            Tv[(lc + 0) * 76 + row] = (_Float16)v.x;
            Tv[(lc + 1) * 76 + row] = (_Float16)v.y;
            Tv[(lc + 2) * 76 + row] = (_Float16)v.z;
            Tv[(lc + 3) * 76 + row] = (_Float16)v.w;
        }
        __syncthreads();
        _Float16* dst = wsV + tileOff;
#pragma unroll
        for (int w = 0; w < 2; ++w) {
            const int c = tid + w * 256;                 // half8 slot 0..511
            const int lane = c & 63, db = (c >> 6) & 3, m = (c >> 8) & 1;
            const int l16 = lane & 15, q = lane >> 4;
            const _Float16* tp = &Tv[(db * 16 + l16) * 76 + m * 32 + q * 4];
            half4 a = *(const half4*)tp;          // keys m*32 + q*4 + 0..3
            half4 b2 = *(const half4*)(tp + 16);  // keys m*32 + 16 + q*4 + 0..3
            half8 o = {a[0], a[1], a[2], a[3], b2[0], b2[1], b2[2], b2[3]};
            *(half8*)(dst + (size_t)c * 8) = o;
        }
    }
}

// ---------------------------------------------------------------------------
// Main kernel: double-buffered 32KB LDS staging of 64-key frag tiles.
// Each wave owns 32 q-rows (2 row-blocks) x 2 sources. All MFMAs K=32.
// ---------------------------------------------------------------------------
__global__ __launch_bounds__(256, 3) void bm_attn_main(
    const float* __restrict__ qw, const float* __restrict__ qm,
    const _Float16* __restrict__ wsK, const _Float16* __restrict__ wsV,
    float* __restrict__ out)
{
    // Bijective XCD swizzle (1024 blocks, 8 XCDs): blocks sharing (bh,set)
    // colocate on one XCD -> its 256KB ws slice stays L2-resident.
    const int hw = (int)blockIdx.x + 16 * (int)blockIdx.y + 512 * (int)blockIdx.z;
    const int work = (hw & 7) * 128 + (hw >> 3);
    const int ltile = work & 15, bh = (work >> 4) & 31, set = work >> 9;

    const int b = bh >> 3, h = bh & 7;
    const float* Q0 = set ? qm : qw;
    const float* Q1 = set ? qw : qm;
    const int c0 = set ? 1 : 0, c1 = set ? 2 : 3;

    const int tid = threadIdx.x;
    const int wave = tid >> 6, lane = tid & 63;
    const int quad = lane >> 4, l16 = lane & 15;

    __shared__ __align__(16) _Float16 ldsK[2][4096];   // 2 x 8 KB
    __shared__ __align__(16) _Float16 ldsV[2][4096];   // 2 x 8 KB

    const size_t headOff = ((size_t)b * 2048) * 512 + (size_t)h * 64;
    const size_t tileBase = (((size_t)set * 32 + bh) * 32) * 4096;
    const _Float16* tK = wsK + tileBase;
    const _Float16* tV = wsV + tileBase;

    // ---- Q B-fragments: [src][row-block][kc], unscaled (K carries scale) ----
    const int rowBase = ltile * 128 + wave * 32;
    half8 qB[2][2][2];
    {
        const float* qs[2] = { Q0 + headOff, Q1 + headOff };
#pragma unroll
        for (int s = 0; s < 2; ++s)
#pragma unroll
            for (int rb = 0; rb < 2; ++rb)
#pragma unroll
                for (int kc = 0; kc < 2; ++kc) {
                    const float* p = qs[s] + (size_t)(rowBase + rb * 16 + l16) * 512 + kc * 32 + quad * 8;
                    float4 x = *(const float4*)p;
                    float4 y = *(const float4*)(p + 4);
                    half2t h0 = pk(x.x, x.y), h1 = pk(x.z, x.w);
                    half2t h2 = pk(y.x, y.y), h3 = pk(y.z, y.w);
                    qB[s][rb][kc] = (half8){h0.x, h0.y, h1.x, h1.y, h2.x, h2.y, h3.x, h3.y};
                }
    }

    f32x4 accO[2][2][4];   // [src][rb][db]
    f32x4 rsD[2][2];       // [src][rb]
#pragma unroll
    for (int s = 0; s < 2; ++s)
#pragma unroll
        for (int rb = 0; rb < 2; ++rb) {
            rsD[s][rb] = (f32x4){0.f, 0.f, 0.f, 0.f};
#pragma unroll
            for (int d = 0; d < 4; ++d) accO[s][rb][d] = (f32x4){0.f, 0.f, 0.f, 0.f};
        }
    const half8 ones8 = {(_Float16)1.f, (_Float16)1.f, (_Float16)1.f, (_Float16)1.f,
                         (_Float16)1.f, (_Float16)1.f, (_Float16)1.f, (_Float16)1.f};

    // ---- stage 64-key tile t into LDS buffer buf (pure linear copy) ----
    auto stage = [&](int t, int buf) {
        const _Float16* gK = tK + (size_t)t * 4096 + tid * 8;
        const _Float16* gV = tV + (size_t)t * 4096 + tid * 8;
        _Float16* lK = &ldsK[buf][wave * 512];   // wave-uniform base; HW adds lane*16B
        _Float16* lV = &ldsV[buf][wave * 512];
        gload_lds16(gK, lK);
        gload_lds16(gK + 2048, lK + 2048);
        gload_lds16(gV, lV);
        gload_lds16(gV + 2048, lV + 2048);
    };

    stage(0, 0);
    __syncthreads();
    int cur = 0;

#pragma unroll 1
    for (int tile = 0; tile < 32; ++tile) {
        if (tile + 1 < 32) stage(tile + 1, cur ^ 1);

        const _Float16* kt = &ldsK[cur][lane * 8];
        const _Float16* vt = &ldsV[cur][lane * 8];
#pragma unroll
        for (int m = 0; m < 2; ++m) {
            // ---- K frags for 32 keys (two 16-key blocks), read once, used 4x
            half8 k00 = *(const half8*)(kt + (m * 4 + 0) * 512);
            half8 k01 = *(const half8*)(kt + (m * 4 + 1) * 512);
            half8 k10 = *(const half8*)(kt + (m * 4 + 2) * 512);
            half8 k11 = *(const half8*)(kt + (m * 4 + 3) * 512);

            half8 pa[2][2];
#pragma unroll
            for (int s = 0; s < 2; ++s)
#pragma unroll
                for (int rb = 0; rb < 2; ++rb) {
                    f32x4 z4 = {0.f, 0.f, 0.f, 0.f};
                    f32x4 slo = MFMA_QK(k00, qB[s][rb][0], z4);
                    slo = MFMA_QK(k01, qB[s][rb][1], slo);      // keys m*32+q*4+r
                    f32x4 shi = MFMA_QK(k10, qB[s][rb][0], z4);
                    shi = MFMA_QK(k11, qB[s][rb][1], shi);      // keys m*32+16+q*4+r

                    half2t e0 = pk(__builtin_amdgcn_exp2f(slo[0]), __builtin_amdgcn_exp2f(slo[1]));
                    half2t e1 = pk(__builtin_amdgcn_exp2f(slo[2]), __builtin_amdgcn_exp2f(slo[3]));
                    half2t e2 = pk(__builtin_amdgcn_exp2f(shi[0]), __builtin_amdgcn_exp2f(shi[1]));
                    half2t e3 = pk(__builtin_amdgcn_exp2f(shi[2]), __builtin_amdgcn_exp2f(shi[3]));
                    half8 p8 = {e0.x, e0.y, e1.x, e1.y, e2.x, e2.y, e3.x, e3.y};
                    pa[s][rb] = p8;
                    // row-sum via ones-MFMA (D reg r = rowsum of qrow=quad*4+r)
                    rsD[s][rb] = MFMA_QK(p8, ones8, rsD[s][rb]);
                }

            // ---- O += P(32 keys) * V(32 keys); each bv read used 4x ----
#pragma unroll
            for (int db = 0; db < 4; ++db) {
                half8 bv = *(const half8*)(vt + (m * 4 + db) * 512);
                accO[0][0][db] = MFMA_QK(pa[0][0], bv, accO[0][0][db]);
                accO[0][1][db] = MFMA_QK(pa[0][1], bv, accO[0][1][db]);
                accO[1][0][db] = MFMA_QK(pa[1][0], bv, accO[1][0][db]);
                accO[1][1][db] = MFMA_QK(pa[1][1], bv, accO[1][1][db]);
            }
        }
        __syncthreads();
        cur ^= 1;
    }

    // ---- epilogue: rsD reg r IS the row-sum for qrow=quad*4+r; no shuffles ----
#pragma unroll
    for (int s = 0; s < 2; ++s) {
        const int c = (s == 0) ? c0 : c1;
        float* ob = out + (size_t)c * TENS_ELEMS + headOff;
#pragma unroll
        for (int rb = 0; rb < 2; ++rb)
#pragma unroll
            for (int r = 0; r < 4; ++r) {
                const float inv = 1.0f / rsD[s][rb][r];
                const int row = rowBase + rb * 16 + quad * 4 + r;
#pragma unroll
                for (int db = 0; db < 4; ++db) {
                    ob[(size_t)row * 512 + db * 16 + l16] = accO[s][rb][db][r] * inv;
                }
            }
    }
}

// ---------------------------------------------------------------------------
// Fallback (ws too small): R4's self-contained LDS-staging kernel.
// ---------------------------------------------------------------------------
__global__ __launch_bounds__(256) void bm_attn_fallback(
    const float* __restrict__ qw, const float* __restrict__ kw, const float* __restrict__ vw,
    const float* __restrict__ qm, const float* __restrict__ km, const float* __restrict__ vm,
    float* __restrict__ out)
{
    const int ltile = blockIdx.x, bh = blockIdx.y, set = blockIdx.z;
    const int b = bh >> 3, h = bh & 7;
    const float* Q0 = set ? qm : qw;
    const float* Q1 = set ? qw : qm;
    const int c0 = set ? 1 : 0, c1 = set ? 2 : 3;
    const int tid = threadIdx.x;
    const int wave = tid >> 6, lane = tid & 63;
    const int quad = lane >> 4, l16 = lane & 15;
    __shared__ __align__(16) _Float16 Kt[64 * 72];
    __shared__ __align__(16) _Float16 Vt[64 * 72];
    const size_t headOff = ((size_t)b * 2048) * 512 + (size_t)h * 64;
    const float* kb = (set ? km : kw) + headOff;
    const float* vb = (set ? vm : vw) + headOff;
    const int rowBase = ltile * 64 + wave * 16;
    half8 qB[2][2];
    {
        const float* qs[2] = { Q0 + headOff, Q1 + headOff };
#pragma unroll
        for (int s = 0; s < 2; ++s)
#pragma unroll
            for (int kc = 0; kc < 2; ++kc) {
                const float* p = qs[s] + (size_t)(rowBase + l16) * 512 + kc * 32 + quad * 8;
                half8 q;
#pragma unroll
                for (int j = 0; j < 8; ++j) q[j] = (_Float16)(p[j] * QSCALE);
                qB[s][kc] = q;
            }
    }
    f32x4 accO[2][4];
#pragma unroll
    for (int s = 0; s < 2; ++s)
#pragma unroll
        for (int d = 0; d < 4; ++d) accO[s][d] = (f32x4){0.f, 0.f, 0.f, 0.f};
    float rs0 = 0.f, rs1 = 0.f;
#pragma unroll 1
    for (int tile = 0; tile < 32; ++tile) {
        const int s0 = tile * 64;
        __syncthreads();
        {
            const int r0 = tid >> 4, f4 = (tid & 15) * 4;
#pragma unroll
            for (int p4 = 0; p4 < 4; ++p4) {
                const int row = p4 * 16 + r0;
                float4 v = *(const float4*)(kb + (size_t)(s0 + row) * 512 + f4);
                half2t a = pk(v.x, v.y), b2 = pk(v.z, v.w);
                half4 o = {a.x, a.y, b2.x, b2.y};
                *(half4*)&Kt[row * 72 + f4] = o;
            }
            const int sl = tid & 63, dq = tid >> 6;
            const float* vrow = vb + (size_t)(s0 + sl) * 512;
#pragma unroll
            for (int i = 0; i < 4; ++i) {
                const int d0 = dq * 16 + i * 4;
                float4 v = *(const float4*)(vrow + d0);
                Vt[(d0 + 0) * 72 + sl] = (_Float16)v.x;
                Vt[(d0 + 1) * 72 + sl] = (_Float16)v.y;
                Vt[(d0 + 2) * 72 + sl] = (_Float16)v.z;
                Vt[(d0 + 3) * 72 + sl] = (_Float16)v.w;
            }
        }
        __syncthreads();
#pragma unroll
        for (int nb = 0; nb < 4; ++nb) {
            half8 k0 = *(const half8*)&Kt[(nb * 16 + l16) * 72 + quad * 8];
            half8 k1 = *(const half8*)&Kt[(nb * 16 + l16) * 72 + 32 + quad * 8];
            f32x4 z = {0.f, 0.f, 0.f, 0.f};
            f32x4 st0 = MFMA_QK(k0, qB[0][0], z);
            st0 = MFMA_QK(k1, qB[0][1], st0);
            f32x4 st1 = MFMA_QK(k0, qB[1][0], z);
            st1 = MFMA_QK(k1, qB[1][1], st1);
            half2t p00 = pk(__builtin_amdgcn_exp2f(st0[0]), __builtin_amdgcn_exp2f(st0[1]));
            half2t p01 = pk(__builtin_amdgcn_exp2f(st0[2]), __builtin_amdgcn_exp2f(st0[3]));
            half2t p10 = pk(__builtin_amdgcn_exp2f(st1[0]), __builtin_amdgcn_exp2f(st1[1]));
            half2t p11 = pk(__builtin_amdgcn_exp2f(st1[2]), __builtin_amdgcn_exp2f(st1[3]));
            rs0 += (float)p00.x + (float)p00.y + (float)p01.x + (float)p01.y;
            rs1 += (float)p10.x + (float)p10.y + (float)p11.x + (float)p11.y;
            half4 ph0 = {p00.x, p00.y, p01.x, p01.y};
            half4 ph1 = {p10.x, p10.y, p11.x, p11.y};
#pragma unroll
            for (int db = 0; db < 4; ++db) {
                half4 bv = *(const half4*)&Vt[(db * 16 + l16) * 72 + nb * 16 + quad * 4];
                accO[0][db] = MFMA_PV(ph0, bv, accO[0][db]);
                accO[1][db] = MFMA_PV(ph1, bv, accO[1][db]);
            }
        }
    }
#pragma unroll
    for (int s = 0; s < 2; ++s) {
        float rs = (s == 0) ? rs0 : rs1;
        rs += __shfl_xor(rs, 16);
        rs += __shfl_xor(rs, 32);
        const float inv = 1.0f / rs;
        const int c = (s == 0) ? c0 : c1;
        float* ob = out + (size_t)c * TENS_ELEMS + headOff;
#pragma unroll
        for (int r = 0; r < 4; ++r) {
            const float invr = __shfl(inv, quad * 4 + r);
            const int row = rowBase + quad * 4 + r;
#pragma unroll
            for (int db = 0; db < 4; ++db) {
                ob[(size_t)row * 512 + db * 16 + l16] = accO[s][db][r] * invr;
            }
        }
    }
}

extern "C" void kernel_launch(void* const* d_in, const int* in_sizes, int n_in,
                              void* d_out, int out_size, void* d_ws, size_t ws_size,
                              hipStream_t stream) {
    const float* qw = (const float*)d_in[0];
    const float* kw = (const float*)d_in[1];
    const float* vw = (const float*)d_in[2];
    const float* qm = (const float*)d_in[3];
    const float* km = (const float*)d_in[4];
    const float* vm = (const float*)d_in[5];
    float* out = (float*)d_out;

    dim3 block(256);
    const size_t NEED = (size_t)4 * TENS_ELEMS * sizeof(_Float16);  // 32 MiB

    if (ws_size >= NEED) {
        _Float16* wsK = (_Float16*)d_ws;                 // [2][32][32][4096] frag-ordered K (scaled)
        _Float16* wsV = wsK + (size_t)2 * TENS_ELEMS;    // [2][32][32][4096] key-permuted K=32 V frags
        prep_kernel<<<dim3(32, 32, 4), block, 0, stream>>>(kw, km, vw, vm, wsK, wsV);
        bm_attn_main<<<dim3(16, 32, 2), block, 0, stream>>>(qw, qm, wsK, wsV, out);
    } else {
        bm_attn_fallback<<<dim3(32, 32, 2), block, 0, stream>>>(qw, kw, vw, qm, km, vm, out);
    }
}